// Round 1
// baseline (201.670 us; speedup 1.0000x reference)
//
#include <hip/hip_runtime.h>

// LJ pair-energy sum: 8.4M random pairs over 262144 particles.
// One thread handles 4 pairs (int4 index loads). Double accumulation from
// the wave-reduce stage up; one double atomicAdd per block into d_ws.

__global__ __launch_bounds__(256) void lj_pairs_kernel(
    const float* __restrict__ x,        // (N,3) float32
    const float* __restrict__ eps_p,    // scalar
    const float* __restrict__ sig_p,    // scalar
    const float* __restrict__ box_p,    // (3,)
    const int4*  __restrict__ idx_i4,   // (n_pairs/4,)
    const int4*  __restrict__ idx_j4,
    double*      __restrict__ acc)
{
    const int t = blockIdx.x * blockDim.x + threadIdx.x;

    const float eps  = eps_p[0];
    const float sig  = sig_p[0];
    const float sig2 = sig * sig;
    const float L0 = box_p[0], L1 = box_p[1], L2 = box_p[2];
    const float i0 = 1.0f / L0, i1 = 1.0f / L1, i2 = 1.0f / L2;

    const int4 ii = idx_i4[t];
    const int4 jj = idx_j4[t];
    const int ia[4] = {ii.x, ii.y, ii.z, ii.w};
    const int ja[4] = {jj.x, jj.y, jj.z, jj.w};

    float sum = 0.0f;
#pragma unroll
    for (int k = 0; k < 4; ++k) {
        const float* pi = x + 3 * ia[k];
        const float* pj = x + 3 * ja[k];
        float dx = pi[0] - pj[0];
        float dy = pi[1] - pj[1];
        float dz = pi[2] - pj[2];
        // minimum image: jnp.round == round-half-even == rintf (RNE default)
        dx -= L0 * rintf(dx * i0);
        dy -= L1 * rintf(dy * i1);
        dz -= L2 * rintf(dz * i2);
        const float r2 = dx * dx + dy * dy + dz * dz;
        const float s2 = sig2 / r2;
        const float s6 = s2 * s2 * s2;
        sum += s6 * s6 - s6;
    }
    // 4*eps factor applied once per thread (exact: distributes over the sum)
    double dsum = (double)(4.0f * eps * sum);

    // wave(64) butterfly reduce in double
    #pragma unroll
    for (int off = 32; off > 0; off >>= 1)
        dsum += __shfl_down(dsum, off, 64);

    __shared__ double wsum[4];
    const int lane = threadIdx.x & 63;
    const int wave = threadIdx.x >> 6;
    if (lane == 0) wsum[wave] = dsum;
    __syncthreads();
    if (threadIdx.x == 0) {
        const double b = wsum[0] + wsum[1] + wsum[2] + wsum[3];
        atomicAdd(acc, b);   // device-scope by default — XCD-safe
    }
}

__global__ void lj_finalize_kernel(const double* __restrict__ acc,
                                   float* __restrict__ out)
{
    out[0] = (float)acc[0];
}

extern "C" void kernel_launch(void* const* d_in, const int* in_sizes, int n_in,
                              void* d_out, int out_size, void* d_ws, size_t ws_size,
                              hipStream_t stream) {
    const float* x     = (const float*)d_in[0];
    const float* eps   = (const float*)d_in[1];
    const float* sigma = (const float*)d_in[2];
    const float* box   = (const float*)d_in[3];
    const int4*  ii    = (const int4*)d_in[4];
    const int4*  jj    = (const int4*)d_in[5];
    float* out = (float*)d_out;
    double* acc = (double*)d_ws;

    const int n_pairs = in_sizes[4];      // 8388608
    const int threads_total = n_pairs / 4; // 2097152, one int4 per thread
    const int block = 256;
    const int grid = threads_total / block; // 8192

    hipMemsetAsync(acc, 0, sizeof(double), stream);  // graph-capture safe
    lj_pairs_kernel<<<grid, block, 0, stream>>>(x, eps, sigma, box, ii, jj, acc);
    lj_finalize_kernel<<<1, 1, 0, stream>>>(acc, out);
}

// Round 3
// 193.393 us; speedup vs baseline: 1.0428x; 1.0428x over previous
//
#include <hip/hip_runtime.h>

// LJ pair-energy sum, round 3 (= round-2 plan with compile fix):
//  - repack x (N,3 f32) into aligned float4 in d_ws -> single-line gathers
//  - index streams loaded non-temporally via native vector type (the HIP
//    int4 class isn't accepted by __builtin_nontemporal_load)
//  - per-block double partials + tiny reduce kernel (no atomics, no memset)

typedef int  vint4  __attribute__((ext_vector_type(4)));

__global__ __launch_bounds__(256) void repack_kernel(
    const float* __restrict__ x, float* __restrict__ xp, int n3)
{
    int t = blockIdx.x * 256 + threadIdx.x;
    if (t < n3) {
        float v = x[t];
        int p = t / 3;
        int c = t - 3 * p;
        xp[4 * p + c] = v;       // .w never read
    }
}

__global__ __launch_bounds__(256) void lj_pairs4_kernel(
    const float4* __restrict__ xp,
    const float* __restrict__ eps_p,
    const float* __restrict__ sig_p,
    const float* __restrict__ box_p,
    const vint4* __restrict__ idx_i4,
    const vint4* __restrict__ idx_j4,
    double*      __restrict__ partial)
{
    const int t = blockIdx.x * blockDim.x + threadIdx.x;

    const float eps  = eps_p[0];
    const float sig  = sig_p[0];
    const float sig2 = sig * sig;
    const float L0 = box_p[0], L1 = box_p[1], L2 = box_p[2];
    const float i0 = 1.0f / L0, i1 = 1.0f / L1, i2 = 1.0f / L2;

    // non-temporal: stream-once data, keep L2 for the position table
    const vint4 ii = __builtin_nontemporal_load(idx_i4 + t);
    const vint4 jj = __builtin_nontemporal_load(idx_j4 + t);
    const int ia[4] = {ii.x, ii.y, ii.z, ii.w};
    const int ja[4] = {jj.x, jj.y, jj.z, jj.w};

    float sum = 0.0f;
#pragma unroll
    for (int k = 0; k < 4; ++k) {
        const float4 pi = xp[ia[k]];
        const float4 pj = xp[ja[k]];
        float dx = pi.x - pj.x;
        float dy = pi.y - pj.y;
        float dz = pi.z - pj.z;
        // jnp.round == round-half-even == rintf (RNE)
        dx -= L0 * rintf(dx * i0);
        dy -= L1 * rintf(dy * i1);
        dz -= L2 * rintf(dz * i2);
        const float r2 = dx * dx + dy * dy + dz * dz;
        const float s2 = sig2 / r2;
        const float s6 = s2 * s2 * s2;
        sum += s6 * s6 - s6;
    }
    double dsum = (double)(4.0f * eps * sum);

    #pragma unroll
    for (int off = 32; off > 0; off >>= 1)
        dsum += __shfl_down(dsum, off, 64);

    __shared__ double wsum[4];
    if ((threadIdx.x & 63) == 0) wsum[threadIdx.x >> 6] = dsum;
    __syncthreads();
    if (threadIdx.x == 0)
        partial[blockIdx.x] = wsum[0] + wsum[1] + wsum[2] + wsum[3];
}

// fallback: unpacked float3 gathers (only if ws too small to repack)
__global__ __launch_bounds__(256) void lj_pairs3_kernel(
    const float* __restrict__ x,
    const float* __restrict__ eps_p,
    const float* __restrict__ sig_p,
    const float* __restrict__ box_p,
    const vint4* __restrict__ idx_i4,
    const vint4* __restrict__ idx_j4,
    double*      __restrict__ partial)
{
    const int t = blockIdx.x * blockDim.x + threadIdx.x;
    const float eps  = eps_p[0];
    const float sig  = sig_p[0];
    const float sig2 = sig * sig;
    const float L0 = box_p[0], L1 = box_p[1], L2 = box_p[2];
    const float i0 = 1.0f / L0, i1 = 1.0f / L1, i2 = 1.0f / L2;

    const vint4 ii = __builtin_nontemporal_load(idx_i4 + t);
    const vint4 jj = __builtin_nontemporal_load(idx_j4 + t);
    const int ia[4] = {ii.x, ii.y, ii.z, ii.w};
    const int ja[4] = {jj.x, jj.y, jj.z, jj.w};

    float sum = 0.0f;
#pragma unroll
    for (int k = 0; k < 4; ++k) {
        const float* pi = x + 3 * ia[k];
        const float* pj = x + 3 * ja[k];
        float dx = pi[0] - pj[0];
        float dy = pi[1] - pj[1];
        float dz = pi[2] - pj[2];
        dx -= L0 * rintf(dx * i0);
        dy -= L1 * rintf(dy * i1);
        dz -= L2 * rintf(dz * i2);
        const float r2 = dx * dx + dy * dy + dz * dz;
        const float s2 = sig2 / r2;
        const float s6 = s2 * s2 * s2;
        sum += s6 * s6 - s6;
    }
    double dsum = (double)(4.0f * eps * sum);
    #pragma unroll
    for (int off = 32; off > 0; off >>= 1)
        dsum += __shfl_down(dsum, off, 64);
    __shared__ double wsum[4];
    if ((threadIdx.x & 63) == 0) wsum[threadIdx.x >> 6] = dsum;
    __syncthreads();
    if (threadIdx.x == 0)
        partial[blockIdx.x] = wsum[0] + wsum[1] + wsum[2] + wsum[3];
}

__global__ __launch_bounds__(256) void reduce_kernel(
    const double* __restrict__ partial, int n, float* __restrict__ out)
{
    double s = 0.0;
    for (int i = threadIdx.x; i < n; i += 256)
        s += partial[i];
    #pragma unroll
    for (int off = 32; off > 0; off >>= 1)
        s += __shfl_down(s, off, 64);
    __shared__ double wsum[4];
    if ((threadIdx.x & 63) == 0) wsum[threadIdx.x >> 6] = s;
    __syncthreads();
    if (threadIdx.x == 0)
        out[0] = (float)(wsum[0] + wsum[1] + wsum[2] + wsum[3]);
}

extern "C" void kernel_launch(void* const* d_in, const int* in_sizes, int n_in,
                              void* d_out, int out_size, void* d_ws, size_t ws_size,
                              hipStream_t stream) {
    const float* x     = (const float*)d_in[0];
    const float* eps   = (const float*)d_in[1];
    const float* sigma = (const float*)d_in[2];
    const float* box   = (const float*)d_in[3];
    const vint4* ii    = (const vint4*)d_in[4];
    const vint4* jj    = (const vint4*)d_in[5];
    float* out = (float*)d_out;

    const int n_pairs = in_sizes[4];            // 8388608
    const int n_part  = in_sizes[0] / 3;        // 262144
    const int block = 256;
    const int grid = (n_pairs / 4) / block;     // 8192 blocks

    const size_t packed_bytes = (size_t)n_part * 16;            // 4 MB
    const size_t partial_bytes = (size_t)grid * sizeof(double); // 64 KB

    if (ws_size >= packed_bytes + partial_bytes) {
        float4* xp = (float4*)d_ws;
        double* partial = (double*)((char*)d_ws + packed_bytes);
        const int n3 = n_part * 3;
        repack_kernel<<<(n3 + block - 1) / block, block, 0, stream>>>(x, (float*)xp, n3);
        lj_pairs4_kernel<<<grid, block, 0, stream>>>(xp, eps, sigma, box, ii, jj, partial);
        reduce_kernel<<<1, block, 0, stream>>>(partial, grid, out);
    } else {
        double* partial = (double*)d_ws;
        lj_pairs3_kernel<<<grid, block, 0, stream>>>(x, eps, sigma, box, ii, jj, partial);
        reduce_kernel<<<1, block, 0, stream>>>(partial, grid, out);
    }
}